// Round 12
// baseline (842.576 us; speedup 1.0000x reference)
//
#include <hip/hip_runtime.h>
#include <cstdint>
#include <cstddef>

// Problem constants (match reference)
#define N_NODES 50000
#define N_EDGES 500000
#define NB 782              // ceil(N_NODES/64) row-blocks
#define NT 150000           // 3 * N_NODES (typed CSR)
#define NCHUNK2 586         // ceil(NT/256) scan chunks
#define FS 49152            // frag halfs per [128x384] matrix (4*24*512)
#define PSTR 136            // LDS row stride in halfs (+8 pad -> bank-spread)
#define MAXOFF 12799744u    // (N_NODES-1)*256 byte-offset clamp
#define ECAP 1024           // LDS csr-slice capacity (mean 213; 4.8x margin)
// C = 128, STEPS = 3, BLOCKS = 2, NUM_ET = 3

typedef _Float16 half8 __attribute__((ext_vector_type(8)));
typedef _Float16 half2v __attribute__((ext_vector_type(2)));
typedef float floatx4 __attribute__((ext_vector_type(4)));

__device__ __forceinline__ float sigmoid_(float x) { return 1.f / (1.f + __expf(-x)); }
__device__ __forceinline__ float tanh_(float x) {
  float t = __expf(-2.f * fabsf(x));
  float r = (1.f - t) / (1.f + t);
  return copysignf(r, x);
}

// ---------------------------------------------------------------- features + edge histogram (merged)
__global__ __launch_bounds__(256) void k_feat_hist(_Float16* __restrict__ h,
    const int* __restrict__ xtype, const int* __restrict__ xtok,
    const float* __restrict__ xs, const int* __restrict__ ei,
    const int* __restrict__ et, int* __restrict__ counts) {
  int idx = blockIdx.x * 256 + threadIdx.x;
  if (idx < N_NODES * 128) {
    int n = idx >> 7, c = idx & 127;
    float v;
    if (c < 32) {
      v = (xtype[n] == c) ? 1.f : 0.f;
    } else if (c < 126) {
      int tk = xtok[n];
      tk = tk < 0 ? 0 : (tk > 93 ? 93 : tk);
      v = (tk == (c - 32)) ? 1.f : 0.f;
    } else {
      v = xs[n * 2 + (c - 126)];
    }
    h[idx] = (_Float16)v;
  }
  if (idx < N_EDGES) {
    int d = ei[N_EDGES + idx];
    int ty = et[idx] & 3;
    if ((unsigned)d < N_NODES && ty < 3) atomicAdd(&counts[ty * N_NODES + d], 1);
  }
}

// ---------------------------------------------------------------- scan phase A: per-chunk sums
__global__ __launch_bounds__(256) void k_scan_a(const int* __restrict__ counts,
    int* __restrict__ bsum) {
  int i = blockIdx.x * 256 + threadIdx.x;
  int v = (i < NT) ? counts[i] : 0;
  int lane = threadIdx.x & 63, wv = threadIdx.x >> 6;
#pragma unroll
  for (int off = 32; off > 0; off >>= 1) v += __shfl_xor(v, off);
  __shared__ int ws[4];
  if (lane == 0) ws[wv] = v;
  __syncthreads();
  if (threadIdx.x == 0) bsum[blockIdx.x] = ws[0] + ws[1] + ws[2] + ws[3];
}

// ---------------------------------------------------------------- scan phase C
__global__ __launch_bounds__(256) void k_scan_c(const int* __restrict__ counts,
    const int* __restrict__ bsum, int* __restrict__ ptr, int* __restrict__ fill) {
  __shared__ int wsum2[4];
  __shared__ int ws[4];
  int lane = threadIdx.x & 63, wv = threadIdx.x >> 6;
  int acc = 0;
  for (int j = threadIdx.x; j < blockIdx.x; j += 256) acc += bsum[j];
#pragma unroll
  for (int off = 32; off > 0; off >>= 1) acc += __shfl_xor(acc, off);
  if (lane == 0) wsum2[wv] = acc;
  __syncthreads();
  int boffset = wsum2[0] + wsum2[1] + wsum2[2] + wsum2[3];
  int i = blockIdx.x * 256 + threadIdx.x;
  int v = (i < NT) ? counts[i] : 0;
  int s = v;
#pragma unroll
  for (int off = 1; off < 64; off <<= 1) { int u = __shfl_up(s, off); if (lane >= off) s += u; }
  if (lane == 63) ws[wv] = s;
  __syncthreads();
  int woff = 0;
#pragma unroll
  for (int w = 0; w < 4; ++w) woff += (w < wv) ? ws[w] : 0;
  int excl = boffset + woff + s - v;
  if (i < NT) { ptr[i] = excl; fill[i] = excl; }
  if (blockIdx.x == NCHUNK2 - 1 && threadIdx.x == 0)
    ptr[NT] = boffset + bsum[NCHUNK2 - 1];
}

// csr stores src row as BYTE offset (src*256) -> no shift/mul in gather
__global__ __launch_bounds__(256) void k_place(const int* __restrict__ ei,
    const int* __restrict__ et, int* __restrict__ fill, int* __restrict__ csr) {
  int e = blockIdx.x * 256 + threadIdx.x;
  if (e >= N_EDGES) return;
  int srcv = ei[e], d = ei[N_EDGES + e], ty = et[e] & 3;
  if ((unsigned)d >= N_NODES || (unsigned)srcv >= N_NODES || ty >= 3) return;
  int pos = atomicAdd(&fill[ty * N_NODES + d], 1);
  if ((unsigned)pos < N_EDGES) csr[pos] = srcv << 8;
}

// ---------------------------------------------------------------- merged weight prep
#define PREP_B (6 * 4 * 24 * 512)
#define PREP_MISC_BLOCKS ((PREP_B + 16384 + 511) / 512)
__global__ __launch_bounds__(512) void k_prep(const float* __restrict__ cw,
    const float* __restrict__ wih, const float* __restrict__ whh,
    const float* __restrict__ hw1, _Float16* __restrict__ dcomb,
    _Float16* __restrict__ dwhh, _Float16* __restrict__ dw1) {
  if (blockIdx.x < 36) {
    int mat = blockIdx.x >> 1, half = blockIdx.x & 1;
    int bt = mat / 3;
    int u = threadIdx.x >> 6, lane = threadIdx.x & 63;
    int quad = lane >> 4, l16 = lane & 15;
    floatx4 zero = {0.f, 0.f, 0.f, 0.f};
    floatx4 acc[4][3];
#pragma unroll
    for (int rt = 0; rt < 4; ++rt)
#pragma unroll
      for (int cc = 0; cc < 3; ++cc) acc[rt][cc] = zero;
#pragma unroll
    for (int jc = 0; jc < 4; ++jc) {
      half8 af[4], bf[3];
#pragma unroll
      for (int rt = 0; rt < 4; ++rt) {
        int m = half * 64 + rt * 16 + l16;
        const float* ap = cw + ((size_t)mat * 128 + m) * 128 + jc * 32 + quad * 8;
        floatx4 a0 = *(const floatx4*)ap;
        floatx4 a1 = *(const floatx4*)(ap + 4);
#pragma unroll
        for (int i = 0; i < 4; ++i) { af[rt][i] = (_Float16)a0[i]; af[rt][4 + i] = (_Float16)a1[i]; }
      }
#pragma unroll
      for (int cc = 0; cc < 3; ++cc) {
        int n = (u * 3 + cc) * 16 + l16;
        const float* bp = wih + ((size_t)bt * 384 + n) * 128 + jc * 32 + quad * 8;
        floatx4 b0 = *(const floatx4*)bp;
        floatx4 b1 = *(const floatx4*)(bp + 4);
#pragma unroll
        for (int i = 0; i < 4; ++i) { bf[cc][i] = (_Float16)b0[i]; bf[cc][4 + i] = (_Float16)b1[i]; }
      }
#pragma unroll
      for (int rt = 0; rt < 4; ++rt)
#pragma unroll
        for (int cc = 0; cc < 3; ++cc)
          acc[rt][cc] = __builtin_amdgcn_mfma_f32_16x16x32_f16(af[rt], bf[cc], acc[rt][cc], 0, 0, 0);
    }
#pragma unroll
    for (int rt = 0; rt < 4; ++rt) {
#pragma unroll
      for (int cc = 0; cc < 3; ++cc) {
        int ctg = u * 3 + cc;
#pragma unroll
        for (int q = 0; q < 4; ++q) {
          int k = half * 64 + rt * 16 + quad * 4 + q;
          int kc2 = k >> 5, r5 = k & 31;
          int lane2 = (r5 >> 3) * 16 + l16, j2 = r5 & 7;
          dcomb[(size_t)mat * FS + (size_t)((kc2 * 24 + ctg) * 64 + lane2) * 8 + j2] =
              (_Float16)acc[rt][cc][q];
        }
      }
    }
  } else {
    int idx0 = (blockIdx.x - 36) * 512 + threadIdx.x;
    if (idx0 < PREP_B) {
      int idx = idx0;
      int j = idx & 7, lane = (idx >> 3) & 63;
      int r = idx >> 9;
      int ct = r % 24;
      int r2 = r / 24;
      int kc = r2 & 3, bt = r2 >> 2;
      int k = kc * 32 + ((lane >> 4) & 3) * 8 + j;
      int n = ct * 16 + (lane & 15);
      dwhh[idx] = (_Float16)whh[((size_t)bt * 384 + n) * 128 + k];
    } else if (idx0 < PREP_B + 16384) {
      int idx = idx0 - PREP_B;
      int j = idx & 7, lane = (idx >> 3) & 63, ct = (idx >> 9) & 7, kc = (idx >> 12) & 3;
      int k = kc * 32 + ((lane >> 4) & 3) * 8 + j;
      int n = ct * 16 + (lane & 15);
      dw1[idx] = (_Float16)hw1[n * 128 + k];
    }
  }
}

// ---------------------------------------------------------------- fused gather + GRU step
// Gather redesign (R12): one WAVE per row (64 lanes x half2 = full 256B row),
// bounds readfirstlane'd to SGPRs -> uniform loop control, 8 predicated
// independent loads (P(deg<=8) ~ 99.2%) into 4 rotating accumulators.
// Per-edge issue slots ~3.5 vs ~7 for the old 16-lane-group scheme.
__global__ __launch_bounds__(512, 4) void k_step(
    const _Float16* __restrict__ Mbase, const size_t mstride,
    _Float16* __restrict__ Sout,
    const int* __restrict__ ptr, const int* __restrict__ csr,
    const _Float16* __restrict__ WPC, const _Float16* __restrict__ WHH,
    const float* __restrict__ bi2, const float* __restrict__ bh2) {
  __shared__ __attribute__((aligned(16))) _Float16 Plds[64 * PSTR];
  __shared__ __attribute__((aligned(16))) _Float16 Mlds[64 * PSTR];
  __shared__ int Elds[ECAP];
  __shared__ int Pt[65];
  int bid = blockIdx.x;
  int t = bid / NB, blk = bid - t * NB;
  int tid = threadIdx.x;
  int wave = tid >> 6, lane = tid & 63;
  int quad = lane >> 4, l16 = lane & 15;
  int rowbase = blk * 64;
  const size_t NC = (size_t)N_NODES * 128;
  const _Float16* Mp = Mbase + mstride * t;
  const char* Mb = (const char*)Mp;
  _Float16* Sp = Sout + (size_t)t * NC;
  const int* ptrT = ptr + t * N_NODES;

  // ---- block-uniform bse/cnt (s_load path)
  int rb64 = rowbase + 64; if (rb64 > N_NODES) rb64 = N_NODES;
  int bse = ptrT[rowbase];
  int cend = ptrT[rb64];
  if (bse < 0) bse = 0; if (bse > N_EDGES) bse = N_EDGES;          // replay safety
  if (cend < bse) cend = bse; if (cend > N_EDGES) cend = N_EDGES;
  int cnt = cend - bse; if (cnt > ECAP) cnt = ECAP;

  // ---- stage ptr slice (relative, clamped)
  if (tid < 65) {
    int n = rowbase + tid; if (n > N_NODES) n = N_NODES;
    int v = ptrT[n] - bse;
    if (v < 0) v = 0; if (v > cnt) v = cnt;
    Pt[tid] = v;
  }
  // ---- stage M block rows (64 x 128 fp16), coalesced
#pragma unroll
  for (int it = 0; it < 2; ++it) {
    int r = it * 32 + (tid >> 4);
    int c = (tid & 15) * 8;
    int gr = rowbase + r; if (gr >= N_NODES) gr = N_NODES - 1;
    half8 v = *(const half8*)(Mp + (size_t)gr * 128 + c);
    *(half8*)(&Mlds[r * PSTR + c]) = v;
  }
  // ---- stage csr slice, offsets clamped here
  for (int i = tid; i < cnt; i += 512) {
    unsigned off = (unsigned)csr[bse + i];
    if (off > MAXOFF) off = 0;
    Elds[i] = (int)off;
  }
  __syncthreads();

  // ---- gather: wave owns rows wave*8 .. wave*8+7, full 64-lane width per row
  unsigned lane4 = (unsigned)(lane * 4);   // byte offset within row (half2/lane)
  for (int r = 0; r < 8; ++r) {
    int nl = wave * 8 + r;
    int b0 = __builtin_amdgcn_readfirstlane(Pt[nl]);
    int e1 = __builtin_amdgcn_readfirstlane(Pt[nl + 1]);
    half2v aa[4] = {{}, {}, {}, {}};
#pragma unroll
    for (int uu = 0; uu < 8; ++uu) {
      if (b0 + uu < e1) {
        unsigned o = (unsigned)Elds[b0 + uu] + lane4;
        aa[uu & 3] += *(const half2v*)(Mb + o);
      }
    }
    for (int i = b0 + 8; i < e1; ++i) {      // rare (deg > 8)
      unsigned o = (unsigned)Elds[i] + lane4;
      aa[i & 3] += *(const half2v*)(Mb + o);
    }
    half2v acc = (aa[0] + aa[1]) + (aa[2] + aa[3]);
    *(half2v*)(&Plds[nl * PSTR + lane * 2]) = acc;
  }
  __syncthreads();

  // ---- MFMA GRU. u = wave owns cts {u (r), 8+u (z), 16+u (n)}.
  const half8* wpc = (const half8*)(WPC + (size_t)t * 3 * FS);
  const half8* whh = (const half8*)(WHH + (size_t)t * FS);
  const float* bi = bi2 + (size_t)t * 384;
  const float* bh = bh2 + (size_t)t * 384;
  int u = wave;
  floatx4 zero = {0.f, 0.f, 0.f, 0.f};
  floatx4 aR[4], aZ[4], aNP[4], aNM[4];
#pragma unroll
  for (int rt = 0; rt < 4; ++rt) { aR[rt] = zero; aZ[rt] = zero; aNP[rt] = zero; aNM[rt] = zero; }
#pragma unroll
  for (int kc = 0; kc < 4; ++kc) {   // gi part: P @ Wcomb
    half8 af[4];
#pragma unroll
    for (int rt = 0; rt < 4; ++rt)
      af[rt] = *(const half8*)(&Plds[(rt * 16 + l16) * PSTR + kc * 32 + quad * 8]);
    half8 br = wpc[(kc * 24 + u) * 64 + lane];
    half8 bz = wpc[(kc * 24 + 8 + u) * 64 + lane];
    half8 bn = wpc[(kc * 24 + 16 + u) * 64 + lane];
#pragma unroll
    for (int rt = 0; rt < 4; ++rt) {
      aR[rt] = __builtin_amdgcn_mfma_f32_16x16x32_f16(af[rt], br, aR[rt], 0, 0, 0);
      aZ[rt] = __builtin_amdgcn_mfma_f32_16x16x32_f16(af[rt], bz, aZ[rt], 0, 0, 0);
      aNP[rt] = __builtin_amdgcn_mfma_f32_16x16x32_f16(af[rt], bn, aNP[rt], 0, 0, 0);
    }
  }
#pragma unroll
  for (int kc = 0; kc < 4; ++kc) {   // gh part: M @ whh.T
    half8 af[4];
#pragma unroll
    for (int rt = 0; rt < 4; ++rt)
      af[rt] = *(const half8*)(&Mlds[(rt * 16 + l16) * PSTR + kc * 32 + quad * 8]);
    half8 br = whh[(kc * 24 + u) * 64 + lane];
    half8 bz = whh[(kc * 24 + 8 + u) * 64 + lane];
    half8 bn = whh[(kc * 24 + 16 + u) * 64 + lane];
#pragma unroll
    for (int rt = 0; rt < 4; ++rt) {
      aR[rt] = __builtin_amdgcn_mfma_f32_16x16x32_f16(af[rt], br, aR[rt], 0, 0, 0);
      aZ[rt] = __builtin_amdgcn_mfma_f32_16x16x32_f16(af[rt], bz, aZ[rt], 0, 0, 0);
      aNM[rt] = __builtin_amdgcn_mfma_f32_16x16x32_f16(af[rt], bn, aNM[rt], 0, 0, 0);
    }
  }
  // ---- epilogue: compute into Plds (dead), then coalesced store-out
  __syncthreads();
  int col = u * 16 + l16;
  float br_ = bi[col] + bh[col];
  float bz_ = bi[128 + col] + bh[128 + col];
  float bin = bi[256 + col], bhn = bh[256 + col];
#pragma unroll
  for (int rt = 0; rt < 4; ++rt) {
#pragma unroll
    for (int q = 0; q < 4; ++q) {
      int lr = rt * 16 + quad * 4 + q;
      float r = sigmoid_(aR[rt][q] + br_);
      float z = sigmoid_(aZ[rt][q] + bz_);
      float nt = tanh_(aNP[rt][q] + bin + r * (aNM[rt][q] + bhn));
      float hold = (float)Mlds[lr * PSTR + col];
      Plds[lr * PSTR + col] = (_Float16)((1.f - z) * nt + z * hold);
    }
  }
  __syncthreads();
#pragma unroll
  for (int it = 0; it < 2; ++it) {
    int r = it * 32 + (tid >> 4);
    int c = (tid & 15) * 8;
    int row = rowbase + r;
    if (row < N_NODES)
      *(half8*)(Sp + (size_t)row * 128 + c) = *(const half8*)(&Plds[r * PSTR + c]);
  }
}

// ---------------------------------------------------------------- LayerNorm (vectorized)
__global__ __launch_bounds__(256) void k_ln16(_Float16* __restrict__ h,
    const _Float16* __restrict__ S, const float* __restrict__ gamma,
    const float* __restrict__ beta) {
  int wave = threadIdx.x >> 6, lane = threadIdx.x & 63;
  int g = lane >> 4, l16 = lane & 15;
  int row = blockIdx.x * 16 + wave * 4 + g;
  if (row >= N_NODES) return;
  const size_t NC = (size_t)N_NODES * 128;
  size_t base = (size_t)row * 128 + l16 * 8;
  half8 hv = *(const half8*)(h + base);
  half8 s0 = *(const half8*)(S + base);
  half8 s1 = *(const half8*)(S + NC + base);
  half8 s2 = *(const half8*)(S + 2 * NC + base);
  float v[8];
  float s = 0.f, sq = 0.f;
#pragma unroll
  for (int i = 0; i < 8; ++i) {
    v[i] = (float)hv[i] + (float)s0[i] + (float)s1[i] + (float)s2[i];
    s += v[i]; sq += v[i] * v[i];
  }
#pragma unroll
  for (int off = 1; off < 16; off <<= 1) {
    s += __shfl_xor(s, off);
    sq += __shfl_xor(sq, off);
  }
  float mu = s * 0.0078125f;
  float var = sq * 0.0078125f - mu * mu;
  float rs = rsqrtf(var + 1e-5f);
  half8 ov;
#pragma unroll
  for (int i = 0; i < 8; ++i) {
    float o = (v[i] - mu) * rs * gamma[l16 * 8 + i] + beta[l16 * 8 + i];
    ov[i] = (_Float16)fmaxf(o, 0.f);
  }
  *(half8*)(h + base) = ov;
}

// ---------------------------------------------------------------- fused LN + head
__global__ __launch_bounds__(256, 4) void k_head(const _Float16* __restrict__ h,
    const _Float16* __restrict__ S, const float* __restrict__ gamma,
    const float* __restrict__ beta, const _Float16* __restrict__ Wf,
    const float* __restrict__ bias, const float* __restrict__ w2,
    const float* __restrict__ b2, float* __restrict__ out) {
  __shared__ __attribute__((aligned(16))) _Float16 zA[64 * PSTR];
  __shared__ __attribute__((aligned(16))) _Float16 zB[64 * PSTR];
  __shared__ float w2s[256];
  int wave = threadIdx.x >> 6, lane = threadIdx.x & 63;
  int quad = lane >> 4, l16 = lane & 15;
  int rowbase = blockIdx.x * 64;
  const size_t NC = (size_t)N_NODES * 128;
  w2s[threadIdx.x] = w2[threadIdx.x];
#pragma unroll
  for (int pass = 0; pass < 4; ++pass) {
    int rl = pass * 16 + wave * 4 + quad;
    int row = rowbase + rl; if (row >= N_NODES) row = N_NODES - 1;
    size_t base = (size_t)row * 128 + l16 * 8;
    half8 hv = *(const half8*)(h + base);
    half8 s0 = *(const half8*)(S + base);
    half8 s1 = *(const half8*)(S + NC + base);
    half8 s2 = *(const half8*)(S + 2 * NC + base);
    float v[8];
    float s = 0.f, sq = 0.f;
#pragma unroll
    for (int i = 0; i < 8; ++i) {
      v[i] = (float)hv[i] + (float)s0[i] + (float)s1[i] + (float)s2[i];
      s += v[i]; sq += v[i] * v[i];
    }
#pragma unroll
    for (int off = 1; off < 16; off <<= 1) {
      s += __shfl_xor(s, off);
      sq += __shfl_xor(sq, off);
    }
    float mu = s * 0.0078125f;
    float var = sq * 0.0078125f - mu * mu;
    float rs = rsqrtf(var + 1e-5f);
    half8 ov;
#pragma unroll
    for (int i = 0; i < 8; ++i) {
      float o = (v[i] - mu) * rs * gamma[l16 * 8 + i] + beta[l16 * 8 + i];
      ov[i] = (_Float16)fmaxf(o, 0.f);
    }
    *(half8*)(&zA[rl * PSTR + l16 * 8]) = ov;
  }
  __syncthreads();
  const half8* wf = (const half8*)Wf;
  floatx4 zero = {0.f, 0.f, 0.f, 0.f};
  floatx4 acc[4][2];
#pragma unroll
  for (int rt = 0; rt < 4; ++rt) { acc[rt][0] = zero; acc[rt][1] = zero; }
#pragma unroll
  for (int kc = 0; kc < 4; ++kc) {
    half8 af[4];
#pragma unroll
    for (int rt = 0; rt < 4; ++rt)
      af[rt] = *(const half8*)(&zA[(rt * 16 + l16) * PSTR + kc * 32 + quad * 8]);
    half8 b0 = wf[(kc * 8 + 2 * wave) * 64 + lane];
    half8 b1 = wf[(kc * 8 + 2 * wave + 1) * 64 + lane];
#pragma unroll
    for (int rt = 0; rt < 4; ++rt) {
      acc[rt][0] = __builtin_amdgcn_mfma_f32_16x16x32_f16(af[rt], b0, acc[rt][0], 0, 0, 0);
      acc[rt][1] = __builtin_amdgcn_mfma_f32_16x16x32_f16(af[rt], b1, acc[rt][1], 0, 0, 0);
    }
  }
  int col = wave * 32 + l16;
#pragma unroll
  for (int rt = 0; rt < 4; ++rt) {
#pragma unroll
    for (int q = 0; q < 4; ++q) {
      int lr = rt * 16 + quad * 4 + q;
      zB[lr * PSTR + col] = (_Float16)fmaxf(acc[rt][0][q] + bias[col], 0.f);
      zB[lr * PSTR + col + 16] = (_Float16)fmaxf(acc[rt][1][q] + bias[col + 16], 0.f);
    }
  }
  __syncthreads();
  int tid = threadIdx.x;
  if (tid < 128) {
    int lr = tid >> 1, o = tid & 1;
    int row = rowbase + lr;
    if (row < N_NODES) {
      const float* wr = w2s + o * 128;
      float a = 0.f;
#pragma unroll
      for (int k = 0; k < 128; ++k) a += (float)zB[lr * PSTR + k] * wr[k];
      out[(size_t)row * 2 + o] = a + b2[o];
    }
  }
}

// ================================================================ launch
extern "C" void kernel_launch(void* const* d_in, const int* in_sizes, int n_in,
                              void* d_out, int out_size, void* d_ws, size_t ws_size,
                              hipStream_t stream) {
  const int*   x_type  = (const int*)d_in[0];
  const int*   x_tok   = (const int*)d_in[1];
  const float* x_small = (const float*)d_in[2];
  const int*   eidx    = (const int*)d_in[3];
  const int*   etype   = (const int*)d_in[4];
  const float* conv_w  = (const float*)d_in[5];
  const float* gwih    = (const float*)d_in[6];
  const float* gwhh    = (const float*)d_in[7];
  const float* gbih    = (const float*)d_in[8];
  const float* gbhh    = (const float*)d_in[9];
  const float* ln_g    = (const float*)d_in[10];
  const float* ln_b    = (const float*)d_in[11];
  const float* hw1     = (const float*)d_in[12];
  const float* hb1     = (const float*)d_in[13];
  const float* hw2     = (const float*)d_in[14];
  const float* hb2     = (const float*)d_in[15];
  float* out = (float*)d_out;

  const size_t NC = (size_t)N_NODES * 128;
  char* W = (char*)d_ws;
  size_t off = 0;
  _Float16* h16 = (_Float16*)(W + off);     off += NC * 2;            // 12.8 MB
  _Float16* S0  = (_Float16*)(W + off);     off += 3 * NC * 2;        // 38.4 MB
  _Float16* S1  = (_Float16*)(W + off);     off += 3 * NC * 2;        // 38.4 MB
  int* counts = (int*)(W + off);            off += (size_t)NT * 4;
  int* ptrv   = (int*)(W + off);            off += (size_t)(NT + 1) * 4;
  int* fill   = (int*)(W + off);            off += (size_t)NT * 4;
  int* bsum   = (int*)(W + off);            off += (NCHUNK2 + 1) * 4;
  int* csr    = (int*)(W + off);            off += (size_t)N_EDGES * 4;
  _Float16* WPC = (_Float16*)(W + off);     off += (size_t)18 * FS * 2;
  _Float16* WHH = (_Float16*)(W + off);     off += (size_t)6 * FS * 2;
  _Float16* W1F = (_Float16*)(W + off);     off += (size_t)16384 * 2;

  // ---- per-call prep
  hipMemsetAsync(counts, 0, (size_t)NT * 4, stream);
  k_feat_hist<<<(N_NODES * 128 + 255) / 256, 256, 0, stream>>>(
      h16, x_type, x_tok, x_small, eidx, etype, counts);
  k_scan_a<<<NCHUNK2, 256, 0, stream>>>(counts, bsum);
  k_scan_c<<<NCHUNK2, 256, 0, stream>>>(counts, bsum, ptrv, fill);
  k_place<<<(N_EDGES + 255) / 256, 256, 0, stream>>>(eidx, etype, fill, csr);
  k_prep<<<36 + PREP_MISC_BLOCKS, 512, 0, stream>>>(
      conv_w, gwih, gwhh, hw1, WPC, WHH, W1F);

  // ---- main loop: 2 blocks x 3 steps; fused gather+GRU; ping-pong S0/S1
  for (int b = 0; b < 2; ++b) {
    for (int s = 0; s < 3; ++s) {
      const _Float16* Msrc = (s == 0) ? h16 : ((s == 1) ? S0 : S1);
      size_t mstr = (s == 0) ? 0 : NC;
      _Float16* Sout = (s == 1) ? S1 : S0;
      k_step<<<3 * NB, 512, 0, stream>>>(Msrc, mstr, Sout, ptrv, csr,
          WPC + (size_t)(b * 9 + s) * FS, WHH + (size_t)b * 3 * FS,
          gbih + (size_t)b * 3 * 384, gbhh + (size_t)b * 3 * 384);
    }
    if (b == 0)
      k_ln16<<<(N_NODES + 15) / 16, 256, 0, stream>>>(h16, S0, ln_g, ln_b);
  }
  // ---- fused LN(b=1) + head
  k_head<<<NB, 256, 0, stream>>>(h16, S0, ln_g + 128, ln_b + 128,
                                 W1F, hb1, hw2, hb2, out);
}

// Round 13
// 670.405 us; speedup vs baseline: 1.2568x; 1.2568x over previous
//
#include <hip/hip_runtime.h>
#include <cstdint>
#include <cstddef>

// Problem constants (match reference)
#define N_NODES 50000
#define N_EDGES 500000
#define NB 782              // ceil(N_NODES/64) row-blocks
#define NT 150000           // 3 * N_NODES (typed CSR)
#define NCHUNK2 586         // ceil(NT/256) scan chunks
#define FS 49152            // frag halfs per [128x384] matrix (4*24*512)
#define PSTR 136            // LDS row stride in halfs (+8 pad -> bank-spread)
#define MAXOFF 12799744u    // (N_NODES-1)*256 byte-offset clamp
#define ECAP 1024           // LDS csr-slice capacity (mean 213; 4.8x margin)
// C = 128, STEPS = 3, BLOCKS = 2, NUM_ET = 3

typedef _Float16 half8 __attribute__((ext_vector_type(8)));
typedef _Float16 half2v __attribute__((ext_vector_type(2)));
typedef float floatx4 __attribute__((ext_vector_type(4)));

__device__ __forceinline__ float sigmoid_(float x) { return 1.f / (1.f + __expf(-x)); }
__device__ __forceinline__ float tanh_(float x) {
  float t = __expf(-2.f * fabsf(x));
  float r = (1.f - t) / (1.f + t);
  return copysignf(r, x);
}

// ---------------------------------------------------------------- features + edge histogram (merged)
__global__ __launch_bounds__(256) void k_feat_hist(_Float16* __restrict__ h,
    const int* __restrict__ xtype, const int* __restrict__ xtok,
    const float* __restrict__ xs, const int* __restrict__ ei,
    const int* __restrict__ et, int* __restrict__ counts) {
  int idx = blockIdx.x * 256 + threadIdx.x;
  if (idx < N_NODES * 128) {
    int n = idx >> 7, c = idx & 127;
    float v;
    if (c < 32) {
      v = (xtype[n] == c) ? 1.f : 0.f;
    } else if (c < 126) {
      int tk = xtok[n];
      tk = tk < 0 ? 0 : (tk > 93 ? 93 : tk);
      v = (tk == (c - 32)) ? 1.f : 0.f;
    } else {
      v = xs[n * 2 + (c - 126)];
    }
    h[idx] = (_Float16)v;
  }
  if (idx < N_EDGES) {
    int d = ei[N_EDGES + idx];
    int ty = et[idx] & 3;
    if ((unsigned)d < N_NODES && ty < 3) atomicAdd(&counts[ty * N_NODES + d], 1);
  }
}

// ---------------------------------------------------------------- scan phase A: per-chunk sums
__global__ __launch_bounds__(256) void k_scan_a(const int* __restrict__ counts,
    int* __restrict__ bsum) {
  int i = blockIdx.x * 256 + threadIdx.x;
  int v = (i < NT) ? counts[i] : 0;
  int lane = threadIdx.x & 63, wv = threadIdx.x >> 6;
#pragma unroll
  for (int off = 32; off > 0; off >>= 1) v += __shfl_xor(v, off);
  __shared__ int ws[4];
  if (lane == 0) ws[wv] = v;
  __syncthreads();
  if (threadIdx.x == 0) bsum[blockIdx.x] = ws[0] + ws[1] + ws[2] + ws[3];
}

// ---------------------------------------------------------------- scan phase C
__global__ __launch_bounds__(256) void k_scan_c(const int* __restrict__ counts,
    const int* __restrict__ bsum, int* __restrict__ ptr, int* __restrict__ fill) {
  __shared__ int wsum2[4];
  __shared__ int ws[4];
  int lane = threadIdx.x & 63, wv = threadIdx.x >> 6;
  int acc = 0;
  for (int j = threadIdx.x; j < blockIdx.x; j += 256) acc += bsum[j];
#pragma unroll
  for (int off = 32; off > 0; off >>= 1) acc += __shfl_xor(acc, off);
  if (lane == 0) wsum2[wv] = acc;
  __syncthreads();
  int boffset = wsum2[0] + wsum2[1] + wsum2[2] + wsum2[3];
  int i = blockIdx.x * 256 + threadIdx.x;
  int v = (i < NT) ? counts[i] : 0;
  int s = v;
#pragma unroll
  for (int off = 1; off < 64; off <<= 1) { int u = __shfl_up(s, off); if (lane >= off) s += u; }
  if (lane == 63) ws[wv] = s;
  __syncthreads();
  int woff = 0;
#pragma unroll
  for (int w = 0; w < 4; ++w) woff += (w < wv) ? ws[w] : 0;
  int excl = boffset + woff + s - v;
  if (i < NT) { ptr[i] = excl; fill[i] = excl; }
  if (blockIdx.x == NCHUNK2 - 1 && threadIdx.x == 0)
    ptr[NT] = boffset + bsum[NCHUNK2 - 1];
}

// csr stores src row as BYTE offset (src*256) -> no shift/mul in gather
__global__ __launch_bounds__(256) void k_place(const int* __restrict__ ei,
    const int* __restrict__ et, int* __restrict__ fill, int* __restrict__ csr) {
  int e = blockIdx.x * 256 + threadIdx.x;
  if (e >= N_EDGES) return;
  int srcv = ei[e], d = ei[N_EDGES + e], ty = et[e] & 3;
  if ((unsigned)d >= N_NODES || (unsigned)srcv >= N_NODES || ty >= 3) return;
  int pos = atomicAdd(&fill[ty * N_NODES + d], 1);
  if ((unsigned)pos < N_EDGES) csr[pos] = srcv << 8;
}

// ---------------------------------------------------------------- merged weight prep
#define PREP_B (6 * 4 * 24 * 512)
#define PREP_MISC_BLOCKS ((PREP_B + 16384 + 511) / 512)
__global__ __launch_bounds__(512) void k_prep(const float* __restrict__ cw,
    const float* __restrict__ wih, const float* __restrict__ whh,
    const float* __restrict__ hw1, _Float16* __restrict__ dcomb,
    _Float16* __restrict__ dwhh, _Float16* __restrict__ dw1) {
  if (blockIdx.x < 36) {
    int mat = blockIdx.x >> 1, half = blockIdx.x & 1;
    int bt = mat / 3;
    int u = threadIdx.x >> 6, lane = threadIdx.x & 63;
    int quad = lane >> 4, l16 = lane & 15;
    floatx4 zero = {0.f, 0.f, 0.f, 0.f};
    floatx4 acc[4][3];
#pragma unroll
    for (int rt = 0; rt < 4; ++rt)
#pragma unroll
      for (int cc = 0; cc < 3; ++cc) acc[rt][cc] = zero;
#pragma unroll
    for (int jc = 0; jc < 4; ++jc) {
      half8 af[4], bf[3];
#pragma unroll
      for (int rt = 0; rt < 4; ++rt) {
        int m = half * 64 + rt * 16 + l16;
        const float* ap = cw + ((size_t)mat * 128 + m) * 128 + jc * 32 + quad * 8;
        floatx4 a0 = *(const floatx4*)ap;
        floatx4 a1 = *(const floatx4*)(ap + 4);
#pragma unroll
        for (int i = 0; i < 4; ++i) { af[rt][i] = (_Float16)a0[i]; af[rt][4 + i] = (_Float16)a1[i]; }
      }
#pragma unroll
      for (int cc = 0; cc < 3; ++cc) {
        int n = (u * 3 + cc) * 16 + l16;
        const float* bp = wih + ((size_t)bt * 384 + n) * 128 + jc * 32 + quad * 8;
        floatx4 b0 = *(const floatx4*)bp;
        floatx4 b1 = *(const floatx4*)(bp + 4);
#pragma unroll
        for (int i = 0; i < 4; ++i) { bf[cc][i] = (_Float16)b0[i]; bf[cc][4 + i] = (_Float16)b1[i]; }
      }
#pragma unroll
      for (int rt = 0; rt < 4; ++rt)
#pragma unroll
        for (int cc = 0; cc < 3; ++cc)
          acc[rt][cc] = __builtin_amdgcn_mfma_f32_16x16x32_f16(af[rt], bf[cc], acc[rt][cc], 0, 0, 0);
    }
#pragma unroll
    for (int rt = 0; rt < 4; ++rt) {
#pragma unroll
      for (int cc = 0; cc < 3; ++cc) {
        int ctg = u * 3 + cc;
#pragma unroll
        for (int q = 0; q < 4; ++q) {
          int k = half * 64 + rt * 16 + quad * 4 + q;
          int kc2 = k >> 5, r5 = k & 31;
          int lane2 = (r5 >> 3) * 16 + l16, j2 = r5 & 7;
          dcomb[(size_t)mat * FS + (size_t)((kc2 * 24 + ctg) * 64 + lane2) * 8 + j2] =
              (_Float16)acc[rt][cc][q];
        }
      }
    }
  } else {
    int idx0 = (blockIdx.x - 36) * 512 + threadIdx.x;
    if (idx0 < PREP_B) {
      int idx = idx0;
      int j = idx & 7, lane = (idx >> 3) & 63;
      int r = idx >> 9;
      int ct = r % 24;
      int r2 = r / 24;
      int kc = r2 & 3, bt = r2 >> 2;
      int k = kc * 32 + ((lane >> 4) & 3) * 8 + j;
      int n = ct * 16 + (lane & 15);
      dwhh[idx] = (_Float16)whh[((size_t)bt * 384 + n) * 128 + k];
    } else if (idx0 < PREP_B + 16384) {
      int idx = idx0 - PREP_B;
      int j = idx & 7, lane = (idx >> 3) & 63, ct = (idx >> 9) & 7, kc = (idx >> 12) & 3;
      int k = kc * 32 + ((lane >> 4) & 3) * 8 + j;
      int n = ct * 16 + (lane & 15);
      dw1[idx] = (_Float16)hw1[n * 128 + k];
    }
  }
}

// ---------------------------------------------------------------- fused gather + GRU step
// Gather = R10's measured-best form: 16-lane group owns two rows (A at wave*8+g,
// B at +4) walked concurrently, __any-ballot loop, 4-wide predicated unroll.
// One wave-wide VMEM instruction serves 4 edges (one per group) — the key
// amortization (R12's full-wave variant quadrupled VMEM issue and regressed).
__global__ __launch_bounds__(512, 4) void k_step(
    const _Float16* __restrict__ Mbase, const size_t mstride,
    _Float16* __restrict__ Sout,
    const int* __restrict__ ptr, const int* __restrict__ csr,
    const _Float16* __restrict__ WPC, const _Float16* __restrict__ WHH,
    const float* __restrict__ bi2, const float* __restrict__ bh2) {
  __shared__ __attribute__((aligned(16))) _Float16 Plds[64 * PSTR];
  __shared__ __attribute__((aligned(16))) _Float16 Mlds[64 * PSTR];
  __shared__ int Elds[ECAP];
  __shared__ int Pt[65];
  int bid = blockIdx.x;
  int t = bid / NB, blk = bid - t * NB;
  int tid = threadIdx.x;
  int wave = tid >> 6, lane = tid & 63;
  int quad = lane >> 4, l16 = lane & 15;
  int rowbase = blk * 64;
  const size_t NC = (size_t)N_NODES * 128;
  const _Float16* Mp = Mbase + mstride * t;
  const char* Mb = (const char*)Mp;
  _Float16* Sp = Sout + (size_t)t * NC;
  const int* ptrT = ptr + t * N_NODES;

  // ---- block-uniform bse/cnt (s_load path)
  int rb64 = rowbase + 64; if (rb64 > N_NODES) rb64 = N_NODES;
  int bse = ptrT[rowbase];
  int cend = ptrT[rb64];
  if (bse < 0) bse = 0; if (bse > N_EDGES) bse = N_EDGES;          // replay safety
  if (cend < bse) cend = bse; if (cend > N_EDGES) cend = N_EDGES;
  int cnt = cend - bse; if (cnt > ECAP) cnt = ECAP;

  // ---- stage ptr slice (relative, clamped)
  if (tid < 65) {
    int n = rowbase + tid; if (n > N_NODES) n = N_NODES;
    int v = ptrT[n] - bse;
    if (v < 0) v = 0; if (v > cnt) v = cnt;
    Pt[tid] = v;
  }
  // ---- stage M block rows (64 x 128 fp16), coalesced
#pragma unroll
  for (int it = 0; it < 2; ++it) {
    int r = it * 32 + (tid >> 4);
    int c = (tid & 15) * 8;
    int gr = rowbase + r; if (gr >= N_NODES) gr = N_NODES - 1;
    half8 v = *(const half8*)(Mp + (size_t)gr * 128 + c);
    *(half8*)(&Mlds[r * PSTR + c]) = v;
  }
  // ---- stage csr slice, offsets clamped here (out of the hot loop)
  for (int i = tid; i < cnt; i += 512) {
    unsigned off = (unsigned)csr[bse + i];
    if (off > MAXOFF) off = 0;
    Elds[i] = (int)off;
  }
  __syncthreads();

  // ---- gather: group g owns rows nlA = wave*8+g, nlB = nlA+4 concurrently
  int g = quad;
  unsigned coff = (unsigned)(l16 * 16);
  int nlA = wave * 8 + g, nlB = nlA + 4;
  int iA = Pt[nlA], eA = Pt[nlA + 1];
  int iB = Pt[nlB], eB = Pt[nlB + 1];
  half8 accA = {}, accB = {};
  while (__any(iA < eA || iB < eB)) {
#pragma unroll
    for (int uu = 0; uu < 4; ++uu) {
      if (iA + uu < eA) {
        unsigned o = (unsigned)Elds[iA + uu] + coff;
        accA += *(const half8*)(Mb + o);
      }
      if (iB + uu < eB) {
        unsigned o = (unsigned)Elds[iB + uu] + coff;
        accB += *(const half8*)(Mb + o);
      }
    }
    iA += 4; iB += 4;
  }
  *(half8*)(&Plds[nlA * PSTR + l16 * 8]) = accA;
  *(half8*)(&Plds[nlB * PSTR + l16 * 8]) = accB;
  __syncthreads();

  // ---- MFMA GRU. u = wave owns cts {u (r), 8+u (z), 16+u (n)}.
  const half8* wpc = (const half8*)(WPC + (size_t)t * 3 * FS);
  const half8* whh = (const half8*)(WHH + (size_t)t * FS);
  const float* bi = bi2 + (size_t)t * 384;
  const float* bh = bh2 + (size_t)t * 384;
  int u = wave;
  floatx4 zero = {0.f, 0.f, 0.f, 0.f};
  floatx4 aR[4], aZ[4], aNP[4], aNM[4];
#pragma unroll
  for (int rt = 0; rt < 4; ++rt) { aR[rt] = zero; aZ[rt] = zero; aNP[rt] = zero; aNM[rt] = zero; }
#pragma unroll
  for (int kc = 0; kc < 4; ++kc) {   // gi part: P @ Wcomb
    half8 af[4];
#pragma unroll
    for (int rt = 0; rt < 4; ++rt)
      af[rt] = *(const half8*)(&Plds[(rt * 16 + l16) * PSTR + kc * 32 + quad * 8]);
    half8 br = wpc[(kc * 24 + u) * 64 + lane];
    half8 bz = wpc[(kc * 24 + 8 + u) * 64 + lane];
    half8 bn = wpc[(kc * 24 + 16 + u) * 64 + lane];
#pragma unroll
    for (int rt = 0; rt < 4; ++rt) {
      aR[rt] = __builtin_amdgcn_mfma_f32_16x16x32_f16(af[rt], br, aR[rt], 0, 0, 0);
      aZ[rt] = __builtin_amdgcn_mfma_f32_16x16x32_f16(af[rt], bz, aZ[rt], 0, 0, 0);
      aNP[rt] = __builtin_amdgcn_mfma_f32_16x16x32_f16(af[rt], bn, aNP[rt], 0, 0, 0);
    }
  }
#pragma unroll
  for (int kc = 0; kc < 4; ++kc) {   // gh part: M @ whh.T
    half8 af[4];
#pragma unroll
    for (int rt = 0; rt < 4; ++rt)
      af[rt] = *(const half8*)(&Mlds[(rt * 16 + l16) * PSTR + kc * 32 + quad * 8]);
    half8 br = whh[(kc * 24 + u) * 64 + lane];
    half8 bz = whh[(kc * 24 + 8 + u) * 64 + lane];
    half8 bn = whh[(kc * 24 + 16 + u) * 64 + lane];
#pragma unroll
    for (int rt = 0; rt < 4; ++rt) {
      aR[rt] = __builtin_amdgcn_mfma_f32_16x16x32_f16(af[rt], br, aR[rt], 0, 0, 0);
      aZ[rt] = __builtin_amdgcn_mfma_f32_16x16x32_f16(af[rt], bz, aZ[rt], 0, 0, 0);
      aNM[rt] = __builtin_amdgcn_mfma_f32_16x16x32_f16(af[rt], bn, aNM[rt], 0, 0, 0);
    }
  }
  // ---- epilogue: compute into Plds (dead), then coalesced store-out
  __syncthreads();
  int col = u * 16 + l16;
  float br_ = bi[col] + bh[col];
  float bz_ = bi[128 + col] + bh[128 + col];
  float bin = bi[256 + col], bhn = bh[256 + col];
#pragma unroll
  for (int rt = 0; rt < 4; ++rt) {
#pragma unroll
    for (int q = 0; q < 4; ++q) {
      int lr = rt * 16 + quad * 4 + q;
      float r = sigmoid_(aR[rt][q] + br_);
      float z = sigmoid_(aZ[rt][q] + bz_);
      float nt = tanh_(aNP[rt][q] + bin + r * (aNM[rt][q] + bhn));
      float hold = (float)Mlds[lr * PSTR + col];
      Plds[lr * PSTR + col] = (_Float16)((1.f - z) * nt + z * hold);
    }
  }
  __syncthreads();
#pragma unroll
  for (int it = 0; it < 2; ++it) {
    int r = it * 32 + (tid >> 4);
    int c = (tid & 15) * 8;
    int row = rowbase + r;
    if (row < N_NODES)
      *(half8*)(Sp + (size_t)row * 128 + c) = *(const half8*)(&Plds[r * PSTR + c]);
  }
}

// ---------------------------------------------------------------- LayerNorm (vectorized)
__global__ __launch_bounds__(256) void k_ln16(_Float16* __restrict__ h,
    const _Float16* __restrict__ S, const float* __restrict__ gamma,
    const float* __restrict__ beta) {
  int wave = threadIdx.x >> 6, lane = threadIdx.x & 63;
  int g = lane >> 4, l16 = lane & 15;
  int row = blockIdx.x * 16 + wave * 4 + g;
  if (row >= N_NODES) return;
  const size_t NC = (size_t)N_NODES * 128;
  size_t base = (size_t)row * 128 + l16 * 8;
  half8 hv = *(const half8*)(h + base);
  half8 s0 = *(const half8*)(S + base);
  half8 s1 = *(const half8*)(S + NC + base);
  half8 s2 = *(const half8*)(S + 2 * NC + base);
  float v[8];
  float s = 0.f, sq = 0.f;
#pragma unroll
  for (int i = 0; i < 8; ++i) {
    v[i] = (float)hv[i] + (float)s0[i] + (float)s1[i] + (float)s2[i];
    s += v[i]; sq += v[i] * v[i];
  }
#pragma unroll
  for (int off = 1; off < 16; off <<= 1) {
    s += __shfl_xor(s, off);
    sq += __shfl_xor(sq, off);
  }
  float mu = s * 0.0078125f;
  float var = sq * 0.0078125f - mu * mu;
  float rs = rsqrtf(var + 1e-5f);
  half8 ov;
#pragma unroll
  for (int i = 0; i < 8; ++i) {
    float o = (v[i] - mu) * rs * gamma[l16 * 8 + i] + beta[l16 * 8 + i];
    ov[i] = (_Float16)fmaxf(o, 0.f);
  }
  *(half8*)(h + base) = ov;
}

// ---------------------------------------------------------------- fused LN + head
__global__ __launch_bounds__(256, 4) void k_head(const _Float16* __restrict__ h,
    const _Float16* __restrict__ S, const float* __restrict__ gamma,
    const float* __restrict__ beta, const _Float16* __restrict__ Wf,
    const float* __restrict__ bias, const float* __restrict__ w2,
    const float* __restrict__ b2, float* __restrict__ out) {
  __shared__ __attribute__((aligned(16))) _Float16 zA[64 * PSTR];
  __shared__ __attribute__((aligned(16))) _Float16 zB[64 * PSTR];
  __shared__ float w2s[256];
  int wave = threadIdx.x >> 6, lane = threadIdx.x & 63;
  int quad = lane >> 4, l16 = lane & 15;
  int rowbase = blockIdx.x * 64;
  const size_t NC = (size_t)N_NODES * 128;
  w2s[threadIdx.x] = w2[threadIdx.x];
#pragma unroll
  for (int pass = 0; pass < 4; ++pass) {
    int rl = pass * 16 + wave * 4 + quad;
    int row = rowbase + rl; if (row >= N_NODES) row = N_NODES - 1;
    size_t base = (size_t)row * 128 + l16 * 8;
    half8 hv = *(const half8*)(h + base);
    half8 s0 = *(const half8*)(S + base);
    half8 s1 = *(const half8*)(S + NC + base);
    half8 s2 = *(const half8*)(S + 2 * NC + base);
    float v[8];
    float s = 0.f, sq = 0.f;
#pragma unroll
    for (int i = 0; i < 8; ++i) {
      v[i] = (float)hv[i] + (float)s0[i] + (float)s1[i] + (float)s2[i];
      s += v[i]; sq += v[i] * v[i];
    }
#pragma unroll
    for (int off = 1; off < 16; off <<= 1) {
      s += __shfl_xor(s, off);
      sq += __shfl_xor(sq, off);
    }
    float mu = s * 0.0078125f;
    float var = sq * 0.0078125f - mu * mu;
    float rs = rsqrtf(var + 1e-5f);
    half8 ov;
#pragma unroll
    for (int i = 0; i < 8; ++i) {
      float o = (v[i] - mu) * rs * gamma[l16 * 8 + i] + beta[l16 * 8 + i];
      ov[i] = (_Float16)fmaxf(o, 0.f);
    }
    *(half8*)(&zA[rl * PSTR + l16 * 8]) = ov;
  }
  __syncthreads();
  const half8* wf = (const half8*)Wf;
  floatx4 zero = {0.f, 0.f, 0.f, 0.f};
  floatx4 acc[4][2];
#pragma unroll
  for (int rt = 0; rt < 4; ++rt) { acc[rt][0] = zero; acc[rt][1] = zero; }
#pragma unroll
  for (int kc = 0; kc < 4; ++kc) {
    half8 af[4];
#pragma unroll
    for (int rt = 0; rt < 4; ++rt)
      af[rt] = *(const half8*)(&zA[(rt * 16 + l16) * PSTR + kc * 32 + quad * 8]);
    half8 b0 = wf[(kc * 8 + 2 * wave) * 64 + lane];
    half8 b1 = wf[(kc * 8 + 2 * wave + 1) * 64 + lane];
#pragma unroll
    for (int rt = 0; rt < 4; ++rt) {
      acc[rt][0] = __builtin_amdgcn_mfma_f32_16x16x32_f16(af[rt], b0, acc[rt][0], 0, 0, 0);
      acc[rt][1] = __builtin_amdgcn_mfma_f32_16x16x32_f16(af[rt], b1, acc[rt][1], 0, 0, 0);
    }
  }
  int col = wave * 32 + l16;
#pragma unroll
  for (int rt = 0; rt < 4; ++rt) {
#pragma unroll
    for (int q = 0; q < 4; ++q) {
      int lr = rt * 16 + quad * 4 + q;
      zB[lr * PSTR + col] = (_Float16)fmaxf(acc[rt][0][q] + bias[col], 0.f);
      zB[lr * PSTR + col + 16] = (_Float16)fmaxf(acc[rt][1][q] + bias[col + 16], 0.f);
    }
  }
  __syncthreads();
  int tid = threadIdx.x;
  if (tid < 128) {
    int lr = tid >> 1, o = tid & 1;
    int row = rowbase + lr;
    if (row < N_NODES) {
      const float* wr = w2s + o * 128;
      float a = 0.f;
#pragma unroll
      for (int k = 0; k < 128; ++k) a += (float)zB[lr * PSTR + k] * wr[k];
      out[(size_t)row * 2 + o] = a + b2[o];
    }
  }
}

// ================================================================ launch
extern "C" void kernel_launch(void* const* d_in, const int* in_sizes, int n_in,
                              void* d_out, int out_size, void* d_ws, size_t ws_size,
                              hipStream_t stream) {
  const int*   x_type  = (const int*)d_in[0];
  const int*   x_tok   = (const int*)d_in[1];
  const float* x_small = (const float*)d_in[2];
  const int*   eidx    = (const int*)d_in[3];
  const int*   etype   = (const int*)d_in[4];
  const float* conv_w  = (const float*)d_in[5];
  const float* gwih    = (const float*)d_in[6];
  const float* gwhh    = (const float*)d_in[7];
  const float* gbih    = (const float*)d_in[8];
  const float* gbhh    = (const float*)d_in[9];
  const float* ln_g    = (const float*)d_in[10];
  const float* ln_b    = (const float*)d_in[11];
  const float* hw1     = (const float*)d_in[12];
  const float* hb1     = (const float*)d_in[13];
  const float* hw2     = (const float*)d_in[14];
  const float* hb2     = (const float*)d_in[15];
  float* out = (float*)d_out;

  const size_t NC = (size_t)N_NODES * 128;
  char* W = (char*)d_ws;
  size_t off = 0;
  _Float16* h16 = (_Float16*)(W + off);     off += NC * 2;            // 12.8 MB
  _Float16* S0  = (_Float16*)(W + off);     off += 3 * NC * 2;        // 38.4 MB
  _Float16* S1  = (_Float16*)(W + off);     off += 3 * NC * 2;        // 38.4 MB
  int* counts = (int*)(W + off);            off += (size_t)NT * 4;
  int* ptrv   = (int*)(W + off);            off += (size_t)(NT + 1) * 4;
  int* fill   = (int*)(W + off);            off += (size_t)NT * 4;
  int* bsum   = (int*)(W + off);            off += (NCHUNK2 + 1) * 4;
  int* csr    = (int*)(W + off);            off += (size_t)N_EDGES * 4;
  _Float16* WPC = (_Float16*)(W + off);     off += (size_t)18 * FS * 2;
  _Float16* WHH = (_Float16*)(W + off);     off += (size_t)6 * FS * 2;
  _Float16* W1F = (_Float16*)(W + off);     off += (size_t)16384 * 2;

  // ---- per-call prep
  hipMemsetAsync(counts, 0, (size_t)NT * 4, stream);
  k_feat_hist<<<(N_NODES * 128 + 255) / 256, 256, 0, stream>>>(
      h16, x_type, x_tok, x_small, eidx, etype, counts);
  k_scan_a<<<NCHUNK2, 256, 0, stream>>>(counts, bsum);
  k_scan_c<<<NCHUNK2, 256, 0, stream>>>(counts, bsum, ptrv, fill);
  k_place<<<(N_EDGES + 255) / 256, 256, 0, stream>>>(eidx, etype, fill, csr);
  k_prep<<<36 + PREP_MISC_BLOCKS, 512, 0, stream>>>(
      conv_w, gwih, gwhh, hw1, WPC, WHH, W1F);

  // ---- main loop: 2 blocks x 3 steps; fused gather+GRU; ping-pong S0/S1
  for (int b = 0; b < 2; ++b) {
    for (int s = 0; s < 3; ++s) {
      const _Float16* Msrc = (s == 0) ? h16 : ((s == 1) ? S0 : S1);
      size_t mstr = (s == 0) ? 0 : NC;
      _Float16* Sout = (s == 1) ? S1 : S0;
      k_step<<<3 * NB, 512, 0, stream>>>(Msrc, mstr, Sout, ptrv, csr,
          WPC + (size_t)(b * 9 + s) * FS, WHH + (size_t)b * 3 * FS,
          gbih + (size_t)b * 3 * 384, gbhh + (size_t)b * 3 * 384);
    }
    if (b == 0)
      k_ln16<<<(N_NODES + 15) / 16, 256, 0, stream>>>(h16, S0, ln_g, ln_b);
  }
  // ---- fused LN(b=1) + head
  k_head<<<NB, 256, 0, stream>>>(h16, S0, ln_g + 128, ln_b + 128,
                                 W1F, hb1, hw2, hb2, out);
}